// Round 14
// baseline (1007.359 us; speedup 1.0000x reference)
//
#include <hip/hip_runtime.h>
#include <hip/hip_fp16.h>

typedef unsigned short u16;
typedef unsigned int u32;

#define N_NODE 50000
#define N_EDGE 250000
#define NNZV   500000

typedef __attribute__((ext_vector_type(8))) __bf16 bf16x8;
typedef __attribute__((ext_vector_type(4))) float f32x4;

#define WAITLGKM0() asm volatile("s_waitcnt lgkmcnt(0)" ::: "memory")
#define SBAR() __builtin_amdgcn_s_barrier()
#define SCHEDB() __builtin_amdgcn_sched_barrier(0)

static __device__ __forceinline__ u16 f2bf(float f) {
  union { float f; u32 u; } cv; cv.f = f;
  u32 u = cv.u;
  return (u16)((u + 0x7FFFu + ((u >> 16) & 1u)) >> 16);
}

// packed f32x2 -> bf16x2 (RNE), 1 VALU op
static __device__ __forceinline__ u32 pk_bf16(float lo, float hi) {
  u32 r;
  asm("v_cvt_pk_bf16_f32 %0, %1, %2" : "=v"(r) : "v"(lo), "v"(hi));
  return r;
}

// single f32 -> bf16 via cvt_pk (1 VALU vs ~6 for manual round)
static __device__ __forceinline__ u16 f2bf_fast(float x) {
  return (u16)pk_bf16(x, x);
}

template<typename T>
static __device__ __forceinline__ T ldo(const void* base, u32 off) {
  return *(const T*)((const char*)base + off);
}
template<typename T>
static __device__ __forceinline__ void sto(void* base, u32 off, T v) {
  *(T*)((char*)base + off) = v;
}

// exact-erf gelu via A&S 7.1.26 poly (|erf err| <= 1.5e-7)
static __device__ __forceinline__ float gelu_f(float x) {
  float z = fabsf(x) * 0.70710678118654752f;
  float t = __builtin_amdgcn_rcpf(1.0f + 0.3275911f * z);
  float p = t * (0.254829592f + t * (-0.284496736f + t * (1.421413741f +
            t * (-1.453152027f + t * 1.061405429f))));
  float er = 1.0f - p * __expf(-z * z);
  er = copysignf(er, x);
  return 0.5f * x * (1.0f + er);
}

// weights [in=K][out=N] f32 -> per-wave register-fragment stream (16x16x32):
// [w = n/cpw][ks = k/32][t = (n%cpw)/16][lane = (k%32)/8*16 + n%16][e = k%8]
__global__ void wprep_reg_kernel(const float* __restrict__ in, u16* __restrict__ out,
                                 int K, int N, int cpw) {
  int idx = blockIdx.x * 256 + threadIdx.x;
  if (idx < K * N) {
    int k = idx / N, n = idx % N;
    int w = n / cpw, rem = n % cpw;
    int t = rem >> 4, l15 = rem & 15;
    int ks = k >> 5, gq = (k >> 3) & 3, e = k & 7;
    int steps = K >> 5, tiles = cpw >> 4;
    size_t o = ((((size_t)(w * steps + ks) * tiles + t) * 64) + gq * 16 + l15) * 8 + e;
    out[o] = f2bf(in[(size_t)k * N + n]);
  }
}

// ==================== fused edge MLP =========================================
// 64 rows/block, 512 thr (8 waves x 48 cols gemm1 / 16 cols gemm2).
// B register-streamed from L2 (2-step ping-pong). FULL x (64x384, 48KB) in LDS
// with slot^(row&15) swizzle -> barrier-free K-loops; h overwrites x in place.
// 3 barriers total. LDS 48KB -> 3 blocks/CU (launch_bounds 6 waves/EU).
__global__ __launch_bounds__(512, 6) void edge_fused_kernel(
    const float* __restrict__ node, const float* __restrict__ edge,
    const int* __restrict__ edgeIdx,
    const float* __restrict__ lng, const float* __restrict__ lnb,
    const u16* __restrict__ w1r, const float* __restrict__ b1,
    const u16* __restrict__ w2r, const float* __restrict__ b2,
    __half* __restrict__ e_h, float* __restrict__ out_edge, int store_eh) {
  const int lane = threadIdx.x & 63, wid = threadIdx.x >> 6;   // 0..7
  const int l15 = lane & 15, gq = lane >> 4;
  const int row0 = blockIdx.x * 64;

  __shared__ __align__(16) u16 xp[64 * 384];      // 48 KB: x, then h (in place)

  // ---- B-stream prologue: W1 steps 0,1 into registers ----
  const bf16x8* w1v = (const bf16x8*)w1r + (size_t)wid * (12 * 192) + lane;
  bf16x8 br[2][3];
#define LDB1(s, b) { br[b][0] = w1v[(s) * 192]; br[b][1] = w1v[(s) * 192 + 64]; \
                     br[b][2] = w1v[(s) * 192 + 128]; }
  LDB1(0, 0); LDB1(1, 1);

  // ---- LN + gather: 8 rows/wave ----
  float ga[6], be[6];
#pragma unroll
  for (int s = 0; s < 3; ++s) {
    float2 g2 = *(const float2*)&lng[s * 128 + 2 * lane];
    float2 b2v = *(const float2*)&lnb[s * 128 + 2 * lane];
    ga[2 * s] = g2.x; ga[2 * s + 1] = g2.y;
    be[2 * s] = b2v.x; be[2 * s + 1] = b2v.y;
  }
  {
    u32 oe[8], oa[8], ob[8];
#pragma unroll
    for (int t = 0; t < 8; ++t) {
      int g = row0 + wid * 8 + t; if (g > N_EDGE - 1) g = N_EDGE - 1;
      int2 ab = ldo<int2>(edgeIdx, (u32)g * 8);
      oe[t] = (u32)g * 512 + lane * 8;
      oa[t] = (u32)ab.x * 512 + lane * 8;
      ob[t] = (u32)ab.y * 512 + lane * 8;
    }
    float2 v0[8], v1[8], v2[8];
#pragma unroll
    for (int t = 0; t < 8; ++t) {
      v0[t] = ldo<float2>(edge, oe[t]);
      v1[t] = ldo<float2>(node, oa[t]);
      v2[t] = ldo<float2>(node, ob[t]);
    }
#pragma unroll
    for (int t = 0; t < 8; ++t) {
      float s  = v0[t].x + v0[t].y + v1[t].x + v1[t].y + v2[t].x + v2[t].y;
      float ss = v0[t].x*v0[t].x + v0[t].y*v0[t].y + v1[t].x*v1[t].x +
                 v1[t].y*v1[t].y + v2[t].x*v2[t].x + v2[t].y*v2[t].y;
#pragma unroll
      for (int m = 1; m < 64; m <<= 1) { s += __shfl_xor(s, m); ss += __shfl_xor(ss, m); }
      float mean = s * (1.0f / 384.0f);
      float var  = ss * (1.0f / 384.0f) - mean * mean;
      float rstd = rsqrtf(var + 1e-5f);
      int lr = wid * 8 + t;
      float2 vv[3] = {v0[t], v1[t], v2[t]};
#pragma unroll
      for (int sg = 0; sg < 3; ++sg) {
        float y0 = (vv[sg].x - mean) * rstd * ga[2 * sg]     + be[2 * sg];
        float y1 = (vv[sg].y - mean) * rstd * ga[2 * sg + 1] + be[2 * sg + 1];
        int sl = (sg * 16 + (lane >> 2)) ^ (lr & 15);
        *(u32*)&xp[lr * 384 + sl * 8 + (lane & 3) * 2] = pk_bf16(y0, y1);
      }
    }
  }
  WAITLGKM0(); SCHEDB(); SBAR(); SCHEDB();

  // ---- gemm1: 12 K-steps, barrier-free; wave owns cols [48*wid, +48) ----
  f32x4 acc1[4][3];
#pragma unroll
  for (int nt = 0; nt < 3; ++nt) {
    float bv = b1[wid * 48 + nt * 16 + l15];
#pragma unroll
    for (int m = 0; m < 4; ++m) acc1[m][nt] = (f32x4){bv, bv, bv, bv};
  }
  int aoff[4];
#pragma unroll
  for (int m = 0; m < 4; ++m) aoff[m] = (m * 16 + l15) * 384;

#pragma unroll
  for (int s = 0; s < 12; ++s) {
    const int axi = ((s * 4 + gq) ^ l15) * 8;
    bf16x8 a[4];
#pragma unroll
    for (int m = 0; m < 4; ++m) a[m] = *(const bf16x8*)&xp[aoff[m] + axi];
    __builtin_amdgcn_s_setprio(1);
#pragma unroll
    for (int m = 0; m < 4; ++m)
#pragma unroll
      for (int nt = 0; nt < 3; ++nt)
        acc1[m][nt] = __builtin_amdgcn_mfma_f32_16x16x32_bf16(a[m], br[s & 1][nt], acc1[m][nt], 0, 0, 0);
    __builtin_amdgcn_s_setprio(0);
    if (s + 2 < 12) { LDB1(s + 2, s & 1); }
  }
  SCHEDB(); SBAR(); SCHEDB();   // all x-reads done before h overwrites xp

  // ---- W2 B-stream prologue + gelu -> h into xp (same swizzle, pitch 384) ----
  const bf16x8* w2v = (const bf16x8*)w2r + (size_t)wid * (12 * 64) + lane;
  bf16x8 br2[2];
#define LDB2(s, b) { br2[b] = w2v[(s) * 64]; }
  LDB2(0, 0); LDB2(1, 1);
#pragma unroll
  for (int m = 0; m < 4; ++m)
#pragma unroll
    for (int nt = 0; nt < 3; ++nt) {
      const int c = wid * 48 + nt * 16 + l15;
#pragma unroll
      for (int j = 0; j < 4; ++j) {
        int r = m * 16 + gq * 4 + j;
        xp[r * 384 + (((c >> 3) ^ (r & 15)) * 8) + (c & 7)] = f2bf_fast(gelu_f(acc1[m][nt][j]));
      }
    }
  WAITLGKM0(); SCHEDB(); SBAR(); SCHEDB();

  // ---- gemm2: 12 K-steps, barrier-free; wave owns cols [16*wid, +16) ----
  float b2v = b2[wid * 16 + l15];
  f32x4 acc2[4];
#pragma unroll
  for (int m = 0; m < 4; ++m) acc2[m] = (f32x4){b2v, b2v, b2v, b2v};

#pragma unroll
  for (int g = 0; g < 12; ++g) {
    const int axi = ((g * 4 + gq) ^ l15) * 8;
    bf16x8 a[4];
#pragma unroll
    for (int m = 0; m < 4; ++m) a[m] = *(const bf16x8*)&xp[aoff[m] + axi];
    __builtin_amdgcn_s_setprio(1);
#pragma unroll
    for (int m = 0; m < 4; ++m)
      acc2[m] = __builtin_amdgcn_mfma_f32_16x16x32_bf16(a[m], br2[g & 1], acc2[m], 0, 0, 0);
    __builtin_amdgcn_s_setprio(0);
    if (g + 2 < 12) { LDB2(g + 2, g & 1); }
  }

  // ---- epilogue: own 16 cols ----
  const int col = wid * 16 + l15;
#pragma unroll
  for (int m = 0; m < 4; ++m)
#pragma unroll
    for (int j = 0; j < 4; ++j) {
      int r = row0 + m * 16 + gq * 4 + j;
      if (r < N_EDGE) {
        u32 o4 = (u32)r * 512 + col * 4;
        __half hv = __float2half(acc2[m][j]);
        if (store_eh) sto<__half>(e_h, (u32)r * 256 + col * 2, hv);
        sto<float>(out_edge, o4, ldo<float>(edge, o4) + __half2float(hv));
      }
    }
#undef LDB1
#undef LDB2
}

// ==================== fused node MLP =========================================
// K=256 (8 steps), full x (64x256, 32KB) in LDS; 3 barriers; B reg-streamed.
__global__ __launch_bounds__(512, 6) void node_fused_kernel(
    const float* __restrict__ node, const __half* __restrict__ agg,
    const float* __restrict__ lng, const float* __restrict__ lnb,
    const u16* __restrict__ w1r, const float* __restrict__ b1,
    const u16* __restrict__ w2r, const float* __restrict__ b2,
    float* __restrict__ out_node) {
  const int lane = threadIdx.x & 63, wid = threadIdx.x >> 6;
  const int l15 = lane & 15, gq = lane >> 4;
  const int row0 = blockIdx.x * 64;

  __shared__ __align__(16) u16 xp[64 * 256];      // 32 KB: x, then h

  const bf16x8* w1v = (const bf16x8*)w1r + (size_t)wid * (8 * 128) + lane;
  bf16x8 br[2][2];
#define NLDB1(s, b) { br[b][0] = w1v[(s) * 128]; br[b][1] = w1v[(s) * 128 + 64]; }
  NLDB1(0, 0); NLDB1(1, 1);

  float ga[4], be[4];
#pragma unroll
  for (int s = 0; s < 2; ++s) {
    float2 g2 = *(const float2*)&lng[s * 128 + 2 * lane];
    float2 b2v = *(const float2*)&lnb[s * 128 + 2 * lane];
    ga[2 * s] = g2.x; ga[2 * s + 1] = g2.y;
    be[2 * s] = b2v.x; be[2 * s + 1] = b2v.y;
  }
  {
    float2 v0[8], v1[8];
#pragma unroll
    for (int t = 0; t < 8; ++t) {
      int g = row0 + wid * 8 + t; if (g > N_NODE - 1) g = N_NODE - 1;
      v0[t] = ldo<float2>(node, (u32)g * 512 + lane * 8);
      v1[t] = __half22float2(ldo<__half2>(agg, (u32)g * 256 + lane * 4));
    }
#pragma unroll
    for (int t = 0; t < 8; ++t) {
      float s  = v0[t].x + v0[t].y + v1[t].x + v1[t].y;
      float ss = v0[t].x*v0[t].x + v0[t].y*v0[t].y + v1[t].x*v1[t].x + v1[t].y*v1[t].y;
#pragma unroll
      for (int m = 1; m < 64; m <<= 1) { s += __shfl_xor(s, m); ss += __shfl_xor(ss, m); }
      float mean = s * (1.0f / 256.0f);
      float var  = ss * (1.0f / 256.0f) - mean * mean;
      float rstd = rsqrtf(var + 1e-5f);
      int lr = wid * 8 + t;
      float2 vv[2] = {v0[t], v1[t]};
#pragma unroll
      for (int sg = 0; sg < 2; ++sg) {
        float y0 = (vv[sg].x - mean) * rstd * ga[2 * sg]     + be[2 * sg];
        float y1 = (vv[sg].y - mean) * rstd * ga[2 * sg + 1] + be[2 * sg + 1];
        int sl = (sg * 16 + (lane >> 2)) ^ (lr & 15);
        *(u32*)&xp[lr * 256 + sl * 8 + (lane & 3) * 2] = pk_bf16(y0, y1);
      }
    }
  }
  WAITLGKM0(); SCHEDB(); SBAR(); SCHEDB();

  // ---- gemm1: 8 K-steps barrier-free; wave owns cols [32*wid, +32) ----
  f32x4 acc1[4][2];
#pragma unroll
  for (int nt = 0; nt < 2; ++nt) {
    float bv = b1[wid * 32 + nt * 16 + l15];
#pragma unroll
    for (int m = 0; m < 4; ++m) acc1[m][nt] = (f32x4){bv, bv, bv, bv};
  }
  int aoff[4];
#pragma unroll
  for (int m = 0; m < 4; ++m) aoff[m] = (m * 16 + l15) * 256;

#pragma unroll
  for (int s = 0; s < 8; ++s) {
    const int axi = ((s * 4 + gq) ^ l15) * 8;
    bf16x8 a[4];
#pragma unroll
    for (int m = 0; m < 4; ++m) a[m] = *(const bf16x8*)&xp[aoff[m] + axi];
    __builtin_amdgcn_s_setprio(1);
#pragma unroll
    for (int m = 0; m < 4; ++m)
#pragma unroll
      for (int nt = 0; nt < 2; ++nt)
        acc1[m][nt] = __builtin_amdgcn_mfma_f32_16x16x32_bf16(a[m], br[s & 1][nt], acc1[m][nt], 0, 0, 0);
    __builtin_amdgcn_s_setprio(0);
    if (s + 2 < 8) { NLDB1(s + 2, s & 1); }
  }
  SCHEDB(); SBAR(); SCHEDB();

  // ---- W2 prologue + gelu -> h ----
  const bf16x8* w2v = (const bf16x8*)w2r + (size_t)wid * (8 * 64) + lane;
  bf16x8 br2[2];
#define NLDB2(s, b) { br2[b] = w2v[(s) * 64]; }
  NLDB2(0, 0); NLDB2(1, 1);
#pragma unroll
  for (int m = 0; m < 4; ++m)
#pragma unroll
    for (int nt = 0; nt < 2; ++nt) {
      const int c = wid * 32 + nt * 16 + l15;   // 0..255
#pragma unroll
      for (int j = 0; j < 4; ++j) {
        int r = m * 16 + gq * 4 + j;
        xp[r * 256 + (((c >> 3) ^ (r & 15)) * 8) + (c & 7)] = f2bf_fast(gelu_f(acc1[m][nt][j]));
      }
    }
  WAITLGKM0(); SCHEDB(); SBAR(); SCHEDB();

  // ---- gemm2: 8 K-steps barrier-free; wave owns cols [16*wid, +16) ----
  float b2v = b2[wid * 16 + l15];
  f32x4 acc2[4];
#pragma unroll
  for (int m = 0; m < 4; ++m) acc2[m] = (f32x4){b2v, b2v, b2v, b2v};

#pragma unroll
  for (int g = 0; g < 8; ++g) {
    const int axi = ((g * 4 + gq) ^ l15) * 8;
    bf16x8 a[4];
#pragma unroll
    for (int m = 0; m < 4; ++m) a[m] = *(const bf16x8*)&xp[aoff[m] + axi];
    __builtin_amdgcn_s_setprio(1);
#pragma unroll
    for (int m = 0; m < 4; ++m)
      acc2[m] = __builtin_amdgcn_mfma_f32_16x16x32_bf16(a[m], br2[g & 1], acc2[m], 0, 0, 0);
    __builtin_amdgcn_s_setprio(0);
    if (g + 2 < 8) { NLDB2(g + 2, g & 1); }
  }

  const int col = wid * 16 + l15;
#pragma unroll
  for (int m = 0; m < 4; ++m)
#pragma unroll
    for (int j = 0; j < 4; ++j) {
      int r = row0 + m * 16 + gq * 4 + j;
      if (r < N_NODE) {
        u32 o4 = (u32)r * 512 + col * 4;
        sto<float>(out_node, o4, ldo<float>(node, o4) + acc2[m][j]);
      }
    }
#undef NLDB1
#undef NLDB2
}

// ---------------- scatter (round-7 form): 1 nnz/wave, dense 256B rows --------
__global__ __launch_bounds__(256) void scatter_kernel(
    const int* __restrict__ rows, const int* __restrict__ cols,
    const float* __restrict__ vals,
    const __half* __restrict__ e_h,
    const float* __restrict__ out_edge, const float* __restrict__ edge,
    __half* __restrict__ agg, int use_eh) {
  long t = (long)blockIdx.x * 256 + threadIdx.x;
  int k = (int)(t >> 6);
  int l = (int)(t & 63);
  int r = rows[k], c = cols[k];
  float v = vals[k];
  __half2 h2;
  if (use_eh) {
    h2 = *(const __half2*)&e_h[(size_t)c * 128 + 2 * l];
  } else {
    size_t o = (size_t)c * 128 + 2 * l;
    float2 eo = *(const float2*)&out_edge[o];
    float2 e0 = *(const float2*)&edge[o];
    h2 = __floats2half2_rn(eo.x - e0.x, eo.y - e0.y);
  }
  h2 = __hmul2(h2, __float2half2_rn(v));
  unsafeAtomicAdd((__half2*)&agg[(size_t)r * 128 + 2 * l], h2);
}

extern "C" void kernel_launch(void* const* d_in, const int* in_sizes, int n_in,
                              void* d_out, int out_size, void* d_ws, size_t ws_size,
                              hipStream_t stream) {
  (void)in_sizes; (void)n_in; (void)out_size;
  const float* node    = (const float*)d_in[0];
  const float* edge    = (const float*)d_in[1];
  const int*   edgeIdx = (const int*)d_in[2];
  const int*   e2n_r   = (const int*)d_in[3];
  const int*   e2n_c   = (const int*)d_in[4];
  const float* e2n_v   = (const float*)d_in[5];
  const float* n1g     = (const float*)d_in[6];
  const float* n1b     = (const float*)d_in[7];
  const float* n2g     = (const float*)d_in[8];
  const float* n2b     = (const float*)d_in[9];
  const float* ew1     = (const float*)d_in[10];
  const float* eb1     = (const float*)d_in[11];
  const float* ew2     = (const float*)d_in[12];
  const float* eb2     = (const float*)d_in[13];
  const float* nw1     = (const float*)d_in[14];
  const float* nb1     = (const float*)d_in[15];
  const float* nw2     = (const float*)d_in[16];
  const float* nb2     = (const float*)d_in[17];

  float* out_node = (float*)d_out;
  float* out_edge = out_node + (size_t)N_NODE * 128;

  char* w = (char*)d_ws;
  auto alloc = [&](size_t bytes) { char* p = w; w += (bytes + 255) & ~(size_t)255; return p; };
  u16* ew1r = (u16*)alloc((size_t)384 * 384 * 2);
  u16* ew2r = (u16*)alloc((size_t)384 * 128 * 2);
  u16* nw1r = (u16*)alloc((size_t)256 * 256 * 2);
  u16* nw2r = (u16*)alloc((size_t)256 * 128 * 2);
  __half* agg = (__half*)alloc((size_t)N_NODE * 128 * 2);

  size_t used = (size_t)(w - (char*)d_ws);
  const size_t EH_BYTES = (size_t)N_EDGE * 128 * 2;   // 64 MB
  int use_eh = (ws_size >= used + EH_BYTES) ? 1 : 0;
  __half* e_h = nullptr;
  if (use_eh) e_h = (__half*)alloc(EH_BYTES);

  wprep_reg_kernel<<<(384 * 384 + 255) / 256, 256, 0, stream>>>(ew1, ew1r, 384, 384, 48);
  wprep_reg_kernel<<<(384 * 128 + 255) / 256, 256, 0, stream>>>(ew2, ew2r, 384, 128, 16);
  wprep_reg_kernel<<<(256 * 256 + 255) / 256, 256, 0, stream>>>(nw1, nw1r, 256, 256, 32);
  wprep_reg_kernel<<<(256 * 128 + 255) / 256, 256, 0, stream>>>(nw2, nw2r, 256, 128, 16);
  hipMemsetAsync(agg, 0, (size_t)N_NODE * 128 * 2, stream);

  edge_fused_kernel<<<(N_EDGE + 63) / 64, 512, 0, stream>>>(
      node, edge, edgeIdx, n1g, n1b, ew1r, eb1, ew2r, eb2, e_h, out_edge, use_eh);

  scatter_kernel<<<(NNZV * 64) / 256, 256, 0, stream>>>(
      e2n_r, e2n_c, e2n_v, e_h, out_edge, edge, agg, use_eh);

  node_fused_kernel<<<(N_NODE + 63) / 64, 512, 0, stream>>>(
      node, agg, n2g, n2b, nw1r, nb1, nw2r, nb2, out_node);
}

// Round 15
// 374.239 us; speedup vs baseline: 2.6918x; 2.6918x over previous
//
#include <hip/hip_runtime.h>
#include <hip/hip_fp16.h>

typedef unsigned short u16;
typedef unsigned int u32;

#define N_NODE 50000
#define N_EDGE 250000
#define NNZV   500000

typedef __attribute__((ext_vector_type(8))) __bf16 bf16x8;
typedef __attribute__((ext_vector_type(4))) float f32x4;

#define WAITLGKM0() asm volatile("s_waitcnt lgkmcnt(0)" ::: "memory")
#define SBAR() __builtin_amdgcn_s_barrier()
#define SCHEDB() __builtin_amdgcn_sched_barrier(0)

static __device__ __forceinline__ u16 f2bf(float f) {
  union { float f; u32 u; } cv; cv.f = f;
  u32 u = cv.u;
  return (u16)((u + 0x7FFFu + ((u >> 16) & 1u)) >> 16);
}

// packed f32x2 -> bf16x2 (RNE), 1 VALU op
static __device__ __forceinline__ u32 pk_bf16(float lo, float hi) {
  u32 r;
  asm("v_cvt_pk_bf16_f32 %0, %1, %2" : "=v"(r) : "v"(lo), "v"(hi));
  return r;
}

// single f32 -> bf16 via cvt_pk (1 VALU)
static __device__ __forceinline__ u16 f2bf_fast(float x) {
  return (u16)pk_bf16(x, x);
}

template<typename T>
static __device__ __forceinline__ T ldo(const void* base, u32 off) {
  return *(const T*)((const char*)base + off);
}
template<typename T>
static __device__ __forceinline__ void sto(void* base, u32 off, T v) {
  *(T*)((char*)base + off) = v;
}

// exact-erf gelu via A&S 7.1.26 poly (|erf err| <= 1.5e-7)
static __device__ __forceinline__ float gelu_f(float x) {
  float z = fabsf(x) * 0.70710678118654752f;
  float t = __builtin_amdgcn_rcpf(1.0f + 0.3275911f * z);
  float p = t * (0.254829592f + t * (-0.284496736f + t * (1.421413741f +
            t * (-1.453152027f + t * 1.061405429f))));
  float er = 1.0f - p * __expf(-z * z);
  er = copysignf(er, x);
  return 0.5f * x * (1.0f + er);
}

// weights [in=K][out=N] f32 -> per-wave register-fragment stream (16x16x32):
// [w = n/cpw][ks = k/32][t = (n%cpw)/16][lane = (k%32)/8*16 + n%16][e = k%8]
__global__ void wprep_reg_kernel(const float* __restrict__ in, u16* __restrict__ out,
                                 int K, int N, int cpw) {
  int idx = blockIdx.x * 256 + threadIdx.x;
  if (idx < K * N) {
    int k = idx / N, n = idx % N;
    int w = n / cpw, rem = n % cpw;
    int t = rem >> 4, l15 = rem & 15;
    int ks = k >> 5, gq = (k >> 3) & 3, e = k & 7;
    int steps = K >> 5, tiles = cpw >> 4;
    size_t o = ((((size_t)(w * steps + ks) * tiles + t) * 64) + gq * 16 + l15) * 8 + e;
    out[o] = f2bf(in[(size_t)k * N + n]);
  }
}

// ==================== fused edge MLP =========================================
// 64 rows/block, 512 thr (8 waves x 48 cols gemm1 / 16 cols gemm2).
// B register-streamed from L2 (2-step ping-pong). FULL x (64x384, 48KB) in LDS
// with slot^(row&15) swizzle -> barrier-free K-loops; h overwrites x in place.
// 3 barriers total. launch_bounds(512,4): reg working set needs 128/wave
// (r14 lesson: 6 waves/EU spills catastrophically).
__global__ __launch_bounds__(512, 4) void edge_fused_kernel(
    const float* __restrict__ node, const float* __restrict__ edge,
    const int* __restrict__ edgeIdx,
    const float* __restrict__ lng, const float* __restrict__ lnb,
    const u16* __restrict__ w1r, const float* __restrict__ b1,
    const u16* __restrict__ w2r, const float* __restrict__ b2,
    __half* __restrict__ e_h, float* __restrict__ out_edge, int store_eh) {
  const int lane = threadIdx.x & 63, wid = threadIdx.x >> 6;   // 0..7
  const int l15 = lane & 15, gq = lane >> 4;
  const int row0 = blockIdx.x * 64;

  __shared__ __align__(16) u16 xp[64 * 384];      // 48 KB: x, then h (in place)

  // ---- B-stream prologue: W1 steps 0,1 into registers ----
  const bf16x8* w1v = (const bf16x8*)w1r + (size_t)wid * (12 * 192) + lane;
  bf16x8 br[2][3];
#define LDB1(s, b) { br[b][0] = w1v[(s) * 192]; br[b][1] = w1v[(s) * 192 + 64]; \
                     br[b][2] = w1v[(s) * 192 + 128]; }
  LDB1(0, 0); LDB1(1, 1);

  // ---- LN + gather: 8 rows/wave ----
  float ga[6], be[6];
#pragma unroll
  for (int s = 0; s < 3; ++s) {
    float2 g2 = *(const float2*)&lng[s * 128 + 2 * lane];
    float2 b2v = *(const float2*)&lnb[s * 128 + 2 * lane];
    ga[2 * s] = g2.x; ga[2 * s + 1] = g2.y;
    be[2 * s] = b2v.x; be[2 * s + 1] = b2v.y;
  }
  {
    u32 oe[8], oa[8], ob[8];
#pragma unroll
    for (int t = 0; t < 8; ++t) {
      int g = row0 + wid * 8 + t; if (g > N_EDGE - 1) g = N_EDGE - 1;
      int2 ab = ldo<int2>(edgeIdx, (u32)g * 8);
      oe[t] = (u32)g * 512 + lane * 8;
      oa[t] = (u32)ab.x * 512 + lane * 8;
      ob[t] = (u32)ab.y * 512 + lane * 8;
    }
    float2 v0[8], v1[8], v2[8];
#pragma unroll
    for (int t = 0; t < 8; ++t) {
      v0[t] = ldo<float2>(edge, oe[t]);
      v1[t] = ldo<float2>(node, oa[t]);
      v2[t] = ldo<float2>(node, ob[t]);
    }
#pragma unroll
    for (int t = 0; t < 8; ++t) {
      float s  = v0[t].x + v0[t].y + v1[t].x + v1[t].y + v2[t].x + v2[t].y;
      float ss = v0[t].x*v0[t].x + v0[t].y*v0[t].y + v1[t].x*v1[t].x +
                 v1[t].y*v1[t].y + v2[t].x*v2[t].x + v2[t].y*v2[t].y;
#pragma unroll
      for (int m = 1; m < 64; m <<= 1) { s += __shfl_xor(s, m); ss += __shfl_xor(ss, m); }
      float mean = s * (1.0f / 384.0f);
      float var  = ss * (1.0f / 384.0f) - mean * mean;
      float rstd = rsqrtf(var + 1e-5f);
      int lr = wid * 8 + t;
      float2 vv[3] = {v0[t], v1[t], v2[t]};
#pragma unroll
      for (int sg = 0; sg < 3; ++sg) {
        float y0 = (vv[sg].x - mean) * rstd * ga[2 * sg]     + be[2 * sg];
        float y1 = (vv[sg].y - mean) * rstd * ga[2 * sg + 1] + be[2 * sg + 1];
        int sl = (sg * 16 + (lane >> 2)) ^ (lr & 15);
        *(u32*)&xp[lr * 384 + sl * 8 + (lane & 3) * 2] = pk_bf16(y0, y1);
      }
    }
  }
  WAITLGKM0(); SCHEDB(); SBAR(); SCHEDB();

  // ---- gemm1: 12 K-steps, barrier-free; wave owns cols [48*wid, +48) ----
  f32x4 acc1[4][3];
#pragma unroll
  for (int nt = 0; nt < 3; ++nt) {
    float bv = b1[wid * 48 + nt * 16 + l15];
#pragma unroll
    for (int m = 0; m < 4; ++m) acc1[m][nt] = (f32x4){bv, bv, bv, bv};
  }
  int aoff[4];
#pragma unroll
  for (int m = 0; m < 4; ++m) aoff[m] = (m * 16 + l15) * 384;

#pragma unroll
  for (int s = 0; s < 12; ++s) {
    const int axi = ((s * 4 + gq) ^ l15) * 8;
    bf16x8 a[4];
#pragma unroll
    for (int m = 0; m < 4; ++m) a[m] = *(const bf16x8*)&xp[aoff[m] + axi];
    __builtin_amdgcn_s_setprio(1);
#pragma unroll
    for (int m = 0; m < 4; ++m)
#pragma unroll
      for (int nt = 0; nt < 3; ++nt)
        acc1[m][nt] = __builtin_amdgcn_mfma_f32_16x16x32_bf16(a[m], br[s & 1][nt], acc1[m][nt], 0, 0, 0);
    __builtin_amdgcn_s_setprio(0);
    if (s + 2 < 12) { LDB1(s + 2, s & 1); }
  }
  SCHEDB(); SBAR(); SCHEDB();   // all x-reads done before h overwrites xp

  // ---- W2 B-stream prologue + gelu -> h into xp (same swizzle, pitch 384) ----
  const bf16x8* w2v = (const bf16x8*)w2r + (size_t)wid * (12 * 64) + lane;
  bf16x8 br2[2];
#define LDB2(s, b) { br2[b] = w2v[(s) * 64]; }
  LDB2(0, 0); LDB2(1, 1);
#pragma unroll
  for (int m = 0; m < 4; ++m)
#pragma unroll
    for (int nt = 0; nt < 3; ++nt) {
      const int c = wid * 48 + nt * 16 + l15;
#pragma unroll
      for (int j = 0; j < 4; ++j) {
        int r = m * 16 + gq * 4 + j;
        xp[r * 384 + (((c >> 3) ^ (r & 15)) * 8) + (c & 7)] = f2bf_fast(gelu_f(acc1[m][nt][j]));
      }
    }
  WAITLGKM0(); SCHEDB(); SBAR(); SCHEDB();

  // ---- gemm2: 12 K-steps, barrier-free; wave owns cols [16*wid, +16) ----
  float b2v = b2[wid * 16 + l15];
  f32x4 acc2[4];
#pragma unroll
  for (int m = 0; m < 4; ++m) acc2[m] = (f32x4){b2v, b2v, b2v, b2v};

#pragma unroll
  for (int g = 0; g < 12; ++g) {
    const int axi = ((g * 4 + gq) ^ l15) * 8;
    bf16x8 a[4];
#pragma unroll
    for (int m = 0; m < 4; ++m) a[m] = *(const bf16x8*)&xp[aoff[m] + axi];
    __builtin_amdgcn_s_setprio(1);
#pragma unroll
    for (int m = 0; m < 4; ++m)
      acc2[m] = __builtin_amdgcn_mfma_f32_16x16x32_bf16(a[m], br2[g & 1], acc2[m], 0, 0, 0);
    __builtin_amdgcn_s_setprio(0);
    if (g + 2 < 12) { LDB2(g + 2, g & 1); }
  }

  // ---- epilogue: own 16 cols ----
  const int col = wid * 16 + l15;
#pragma unroll
  for (int m = 0; m < 4; ++m)
#pragma unroll
    for (int j = 0; j < 4; ++j) {
      int r = row0 + m * 16 + gq * 4 + j;
      if (r < N_EDGE) {
        u32 o4 = (u32)r * 512 + col * 4;
        __half hv = __float2half(acc2[m][j]);
        if (store_eh) sto<__half>(e_h, (u32)r * 256 + col * 2, hv);
        sto<float>(out_edge, o4, ldo<float>(edge, o4) + __half2float(hv));
      }
    }
#undef LDB1
#undef LDB2
}

// ==================== fused node MLP =========================================
// K=256 (8 steps), full x (64x256, 32KB) in LDS; 3 barriers; B reg-streamed.
__global__ __launch_bounds__(512, 4) void node_fused_kernel(
    const float* __restrict__ node, const __half* __restrict__ agg,
    const float* __restrict__ lng, const float* __restrict__ lnb,
    const u16* __restrict__ w1r, const float* __restrict__ b1,
    const u16* __restrict__ w2r, const float* __restrict__ b2,
    float* __restrict__ out_node) {
  const int lane = threadIdx.x & 63, wid = threadIdx.x >> 6;
  const int l15 = lane & 15, gq = lane >> 4;
  const int row0 = blockIdx.x * 64;

  __shared__ __align__(16) u16 xp[64 * 256];      // 32 KB: x, then h

  const bf16x8* w1v = (const bf16x8*)w1r + (size_t)wid * (8 * 128) + lane;
  bf16x8 br[2][2];
#define NLDB1(s, b) { br[b][0] = w1v[(s) * 128]; br[b][1] = w1v[(s) * 128 + 64]; }
  NLDB1(0, 0); NLDB1(1, 1);

  float ga[4], be[4];
#pragma unroll
  for (int s = 0; s < 2; ++s) {
    float2 g2 = *(const float2*)&lng[s * 128 + 2 * lane];
    float2 b2v = *(const float2*)&lnb[s * 128 + 2 * lane];
    ga[2 * s] = g2.x; ga[2 * s + 1] = g2.y;
    be[2 * s] = b2v.x; be[2 * s + 1] = b2v.y;
  }
  {
    float2 v0[8], v1[8];
#pragma unroll
    for (int t = 0; t < 8; ++t) {
      int g = row0 + wid * 8 + t; if (g > N_NODE - 1) g = N_NODE - 1;
      v0[t] = ldo<float2>(node, (u32)g * 512 + lane * 8);
      v1[t] = __half22float2(ldo<__half2>(agg, (u32)g * 256 + lane * 4));
    }
#pragma unroll
    for (int t = 0; t < 8; ++t) {
      float s  = v0[t].x + v0[t].y + v1[t].x + v1[t].y;
      float ss = v0[t].x*v0[t].x + v0[t].y*v0[t].y + v1[t].x*v1[t].x + v1[t].y*v1[t].y;
#pragma unroll
      for (int m = 1; m < 64; m <<= 1) { s += __shfl_xor(s, m); ss += __shfl_xor(ss, m); }
      float mean = s * (1.0f / 256.0f);
      float var  = ss * (1.0f / 256.0f) - mean * mean;
      float rstd = rsqrtf(var + 1e-5f);
      int lr = wid * 8 + t;
      float2 vv[2] = {v0[t], v1[t]};
#pragma unroll
      for (int sg = 0; sg < 2; ++sg) {
        float y0 = (vv[sg].x - mean) * rstd * ga[2 * sg]     + be[2 * sg];
        float y1 = (vv[sg].y - mean) * rstd * ga[2 * sg + 1] + be[2 * sg + 1];
        int sl = (sg * 16 + (lane >> 2)) ^ (lr & 15);
        *(u32*)&xp[lr * 256 + sl * 8 + (lane & 3) * 2] = pk_bf16(y0, y1);
      }
    }
  }
  WAITLGKM0(); SCHEDB(); SBAR(); SCHEDB();

  // ---- gemm1: 8 K-steps barrier-free; wave owns cols [32*wid, +32) ----
  f32x4 acc1[4][2];
#pragma unroll
  for (int nt = 0; nt < 2; ++nt) {
    float bv = b1[wid * 32 + nt * 16 + l15];
#pragma unroll
    for (int m = 0; m < 4; ++m) acc1[m][nt] = (f32x4){bv, bv, bv, bv};
  }
  int aoff[4];
#pragma unroll
  for (int m = 0; m < 4; ++m) aoff[m] = (m * 16 + l15) * 256;

#pragma unroll
  for (int s = 0; s < 8; ++s) {
    const int axi = ((s * 4 + gq) ^ l15) * 8;
    bf16x8 a[4];
#pragma unroll
    for (int m = 0; m < 4; ++m) a[m] = *(const bf16x8*)&xp[aoff[m] + axi];
    __builtin_amdgcn_s_setprio(1);
#pragma unroll
    for (int m = 0; m < 4; ++m)
#pragma unroll
      for (int nt = 0; nt < 2; ++nt)
        acc1[m][nt] = __builtin_amdgcn_mfma_f32_16x16x32_bf16(a[m], br[s & 1][nt], acc1[m][nt], 0, 0, 0);
    __builtin_amdgcn_s_setprio(0);
    if (s + 2 < 8) { NLDB1(s + 2, s & 1); }
  }
  SCHEDB(); SBAR(); SCHEDB();

  // ---- W2 prologue + gelu -> h ----
  const bf16x8* w2v = (const bf16x8*)w2r + (size_t)wid * (8 * 64) + lane;
  bf16x8 br2[2];
#define NLDB2(s, b) { br2[b] = w2v[(s) * 64]; }
  NLDB2(0, 0); NLDB2(1, 1);
#pragma unroll
  for (int m = 0; m < 4; ++m)
#pragma unroll
    for (int nt = 0; nt < 2; ++nt) {
      const int c = wid * 32 + nt * 16 + l15;   // 0..255
#pragma unroll
      for (int j = 0; j < 4; ++j) {
        int r = m * 16 + gq * 4 + j;
        xp[r * 256 + (((c >> 3) ^ (r & 15)) * 8) + (c & 7)] = f2bf_fast(gelu_f(acc1[m][nt][j]));
      }
    }
  WAITLGKM0(); SCHEDB(); SBAR(); SCHEDB();

  // ---- gemm2: 8 K-steps barrier-free; wave owns cols [16*wid, +16) ----
  float b2v = b2[wid * 16 + l15];
  f32x4 acc2[4];
#pragma unroll
  for (int m = 0; m < 4; ++m) acc2[m] = (f32x4){b2v, b2v, b2v, b2v};

#pragma unroll
  for (int g = 0; g < 8; ++g) {
    const int axi = ((g * 4 + gq) ^ l15) * 8;
    bf16x8 a[4];
#pragma unroll
    for (int m = 0; m < 4; ++m) a[m] = *(const bf16x8*)&xp[aoff[m] + axi];
    __builtin_amdgcn_s_setprio(1);
#pragma unroll
    for (int m = 0; m < 4; ++m)
      acc2[m] = __builtin_amdgcn_mfma_f32_16x16x32_bf16(a[m], br2[g & 1], acc2[m], 0, 0, 0);
    __builtin_amdgcn_s_setprio(0);
    if (g + 2 < 8) { NLDB2(g + 2, g & 1); }
  }

  const int col = wid * 16 + l15;
#pragma unroll
  for (int m = 0; m < 4; ++m)
#pragma unroll
    for (int j = 0; j < 4; ++j) {
      int r = row0 + m * 16 + gq * 4 + j;
      if (r < N_NODE) {
        u32 o4 = (u32)r * 512 + col * 4;
        sto<float>(out_node, o4, ldo<float>(node, o4) + acc2[m][j]);
      }
    }
#undef NLDB1
#undef NLDB2
}

// ---------------- scatter: 1 nnz/wave, dense 256B rows; scalar nnz loads -----
__global__ __launch_bounds__(256) void scatter_kernel(
    const int* __restrict__ rows, const int* __restrict__ cols,
    const float* __restrict__ vals,
    const __half* __restrict__ e_h,
    const float* __restrict__ out_edge, const float* __restrict__ edge,
    __half* __restrict__ agg, int use_eh) {
  int k = __builtin_amdgcn_readfirstlane(blockIdx.x * 4 + (threadIdx.x >> 6));
  int l = threadIdx.x & 63;
  int r = rows[k], c = cols[k];
  float v = vals[k];
  __half2 h2;
  if (use_eh) {
    h2 = *(const __half2*)&e_h[(size_t)c * 128 + 2 * l];
  } else {
    size_t o = (size_t)c * 128 + 2 * l;
    float2 eo = *(const float2*)&out_edge[o];
    float2 e0 = *(const float2*)&edge[o];
    h2 = __floats2half2_rn(eo.x - e0.x, eo.y - e0.y);
  }
  h2 = __hmul2(h2, __float2half2_rn(v));
  unsafeAtomicAdd((__half2*)&agg[(size_t)r * 128 + 2 * l], h2);
}

extern "C" void kernel_launch(void* const* d_in, const int* in_sizes, int n_in,
                              void* d_out, int out_size, void* d_ws, size_t ws_size,
                              hipStream_t stream) {
  (void)in_sizes; (void)n_in; (void)out_size;
  const float* node    = (const float*)d_in[0];
  const float* edge    = (const float*)d_in[1];
  const int*   edgeIdx = (const int*)d_in[2];
  const int*   e2n_r   = (const int*)d_in[3];
  const int*   e2n_c   = (const int*)d_in[4];
  const float* e2n_v   = (const float*)d_in[5];
  const float* n1g     = (const float*)d_in[6];
  const float* n1b     = (const float*)d_in[7];
  const float* n2g     = (const float*)d_in[8];
  const float* n2b     = (const float*)d_in[9];
  const float* ew1     = (const float*)d_in[10];
  const float* eb1     = (const float*)d_in[11];
  const float* ew2     = (const float*)d_in[12];
  const float* eb2     = (const float*)d_in[13];
  const float* nw1     = (const float*)d_in[14];
  const float* nb1     = (const float*)d_in[15];
  const float* nw2     = (const float*)d_in[16];
  const float* nb2     = (const float*)d_in[17];

  float* out_node = (float*)d_out;
  float* out_edge = out_node + (size_t)N_NODE * 128;

  char* w = (char*)d_ws;
  auto alloc = [&](size_t bytes) { char* p = w; w += (bytes + 255) & ~(size_t)255; return p; };
  u16* ew1r = (u16*)alloc((size_t)384 * 384 * 2);
  u16* ew2r = (u16*)alloc((size_t)384 * 128 * 2);
  u16* nw1r = (u16*)alloc((size_t)256 * 256 * 2);
  u16* nw2r = (u16*)alloc((size_t)256 * 128 * 2);
  __half* agg = (__half*)alloc((size_t)N_NODE * 128 * 2);

  size_t used = (size_t)(w - (char*)d_ws);
  const size_t EH_BYTES = (size_t)N_EDGE * 128 * 2;   // 64 MB
  int use_eh = (ws_size >= used + EH_BYTES) ? 1 : 0;
  __half* e_h = nullptr;
  if (use_eh) e_h = (__half*)alloc(EH_BYTES);

  wprep_reg_kernel<<<(384 * 384 + 255) / 256, 256, 0, stream>>>(ew1, ew1r, 384, 384, 48);
  wprep_reg_kernel<<<(384 * 128 + 255) / 256, 256, 0, stream>>>(ew2, ew2r, 384, 128, 16);
  wprep_reg_kernel<<<(256 * 256 + 255) / 256, 256, 0, stream>>>(nw1, nw1r, 256, 256, 32);
  wprep_reg_kernel<<<(256 * 128 + 255) / 256, 256, 0, stream>>>(nw2, nw2r, 256, 128, 16);
  hipMemsetAsync(agg, 0, (size_t)N_NODE * 128 * 2, stream);

  edge_fused_kernel<<<(N_EDGE + 63) / 64, 512, 0, stream>>>(
      node, edge, edgeIdx, n1g, n1b, ew1r, eb1, ew2r, eb2, e_h, out_edge, use_eh);

  scatter_kernel<<<(NNZV + 3) / 4, 256, 0, stream>>>(
      e2n_r, e2n_c, e2n_v, e_h, out_edge, edge, agg, use_eh);

  node_fused_kernel<<<(N_NODE + 63) / 64, 512, 0, stream>>>(
      node, agg, n2g, n2b, nw1r, nb1, nw2r, nb2, out_node);
}

// Round 16
// 346.527 us; speedup vs baseline: 2.9070x; 1.0800x over previous
//
#include <hip/hip_runtime.h>
#include <hip/hip_fp16.h>

typedef unsigned short u16;
typedef unsigned int u32;

#define N_NODE 50000
#define N_EDGE 250000
#define NNZV   500000

typedef __attribute__((ext_vector_type(8))) __bf16 bf16x8;
typedef __attribute__((ext_vector_type(4))) float f32x4;

#define WAITLGKM0() asm volatile("s_waitcnt lgkmcnt(0)" ::: "memory")
#define SBAR() __builtin_amdgcn_s_barrier()
#define SCHEDB() __builtin_amdgcn_sched_barrier(0)

static __device__ __forceinline__ u16 f2bf(float f) {
  union { float f; u32 u; } cv; cv.f = f;
  u32 u = cv.u;
  return (u16)((u + 0x7FFFu + ((u >> 16) & 1u)) >> 16);
}

// packed f32x2 -> bf16x2 (RNE), 1 VALU op
static __device__ __forceinline__ u32 pk_bf16(float lo, float hi) {
  u32 r;
  asm("v_cvt_pk_bf16_f32 %0, %1, %2" : "=v"(r) : "v"(lo), "v"(hi));
  return r;
}

// single f32 -> bf16 via cvt_pk (1 VALU)
static __device__ __forceinline__ u16 f2bf_fast(float x) {
  return (u16)pk_bf16(x, x);
}

template<typename T>
static __device__ __forceinline__ T ldo(const void* base, u32 off) {
  return *(const T*)((const char*)base + off);
}
template<typename T>
static __device__ __forceinline__ void sto(void* base, u32 off, T v) {
  *(T*)((char*)base + off) = v;
}

// exact-erf gelu via A&S 7.1.26 poly (|erf err| <= 1.5e-7)
static __device__ __forceinline__ float gelu_f(float x) {
  float z = fabsf(x) * 0.70710678118654752f;
  float t = __builtin_amdgcn_rcpf(1.0f + 0.3275911f * z);
  float p = t * (0.254829592f + t * (-0.284496736f + t * (1.421413741f +
            t * (-1.453152027f + t * 1.061405429f))));
  float er = 1.0f - p * __expf(-z * z);
  er = copysignf(er, x);
  return 0.5f * x * (1.0f + er);
}

// weights [in=K][out=N] f32 -> per-wave register-fragment stream (16x16x32):
// [w = n/cpw][ks = k/32][t = (n%cpw)/16][lane = (k%32)/8*16 + n%16][e = k%8]
static __device__ __forceinline__ void wconv(const float* __restrict__ in,
                                             u16* __restrict__ out,
                                             int K, int N, int cpw, int idx) {
  int k = idx / N, n = idx % N;
  int w = n / cpw, rem = n % cpw;
  int t = rem >> 4, l15 = rem & 15;
  int ks = k >> 5, gq = (k >> 3) & 3, e = k & 7;
  int steps = K >> 5, tiles = cpw >> 4;
  size_t o = ((((size_t)(w * steps + ks) * tiles + t) * 64) + gq * 16 + l15) * 8 + e;
  out[o] = f2bf(in[(size_t)k * N + n]);
}

// merged prep: 4 weight re-layouts + agg zero-fill, one launch
__global__ __launch_bounds__(256) void prep_kernel(
    const float* __restrict__ ew1, const float* __restrict__ ew2,
    const float* __restrict__ nw1, const float* __restrict__ nw2,
    u16* __restrict__ ew1r, u16* __restrict__ ew2r,
    u16* __restrict__ nw1r, u16* __restrict__ nw2r,
    u32* __restrict__ agg0) {
  const int S1 = 384 * 384, S2 = 384 * 128, S3 = 256 * 256, S4 = 256 * 128;
  const int SA = N_NODE * 128 / 2;   // agg as u32
  const long total = (long)S1 + S2 + S3 + S4 + SA;
  for (long i = (long)blockIdx.x * 256 + threadIdx.x; i < total;
       i += (long)gridDim.x * 256) {
    long idx = i;
    if (idx < S1) { wconv(ew1, ew1r, 384, 384, 48, (int)idx); continue; }
    idx -= S1;
    if (idx < S2) { wconv(ew2, ew2r, 384, 128, 16, (int)idx); continue; }
    idx -= S2;
    if (idx < S3) { wconv(nw1, nw1r, 256, 256, 32, (int)idx); continue; }
    idx -= S3;
    if (idx < S4) { wconv(nw2, nw2r, 256, 128, 16, (int)idx); continue; }
    idx -= S4;
    agg0[idx] = 0;
  }
}

// ==================== fused edge MLP =========================================
// 64 rows/block, 512 thr (8 waves x 48 cols gemm1 / 16 cols gemm2).
// B register-streamed from L2 (2-step ping-pong). FULL x (64x384, 48KB) in LDS
// (slot^(row&15) swizzle) -> barrier-free K-loops; h overwrites x in place.
// Edge residual cached in 32KB LDS (loaded once at LN) -> no epilogue HBM
// re-read. LDS 80KB -> 2 blocks/CU. launch_bounds(512,4) (r14: 6/EU spills).
__global__ __launch_bounds__(512, 4) void edge_fused_kernel(
    const float* __restrict__ node, const float* __restrict__ edge,
    const int* __restrict__ edgeIdx,
    const float* __restrict__ lng, const float* __restrict__ lnb,
    const u16* __restrict__ w1r, const float* __restrict__ b1,
    const u16* __restrict__ w2r, const float* __restrict__ b2,
    __half* __restrict__ e_h, float* __restrict__ out_edge, int store_eh) {
  const int lane = threadIdx.x & 63, wid = threadIdx.x >> 6;   // 0..7
  const int l15 = lane & 15, gq = lane >> 4;
  const int row0 = blockIdx.x * 64;

  __shared__ __align__(16) u16 xp[64 * 384];      // 48 KB: x, then h (in place)
  __shared__ __align__(16) float er[64 * 128];    // 32 KB: edge residual cache

  // ---- B-stream prologue: W1 steps 0,1 into registers ----
  const bf16x8* w1v = (const bf16x8*)w1r + (size_t)wid * (12 * 192) + lane;
  bf16x8 br[2][3];
#define LDB1(s, b) { br[b][0] = w1v[(s) * 192]; br[b][1] = w1v[(s) * 192 + 64]; \
                     br[b][2] = w1v[(s) * 192 + 128]; }
  LDB1(0, 0); LDB1(1, 1);

  // ---- LN + gather: 8 rows/wave ----
  float ga[6], be[6];
#pragma unroll
  for (int s = 0; s < 3; ++s) {
    float2 g2 = *(const float2*)&lng[s * 128 + 2 * lane];
    float2 b2v = *(const float2*)&lnb[s * 128 + 2 * lane];
    ga[2 * s] = g2.x; ga[2 * s + 1] = g2.y;
    be[2 * s] = b2v.x; be[2 * s + 1] = b2v.y;
  }
  {
    u32 oe[8], oa[8], ob[8];
#pragma unroll
    for (int t = 0; t < 8; ++t) {
      int g = row0 + wid * 8 + t; if (g > N_EDGE - 1) g = N_EDGE - 1;
      int2 ab = ldo<int2>(edgeIdx, (u32)g * 8);
      oe[t] = (u32)g * 512 + lane * 8;
      oa[t] = (u32)ab.x * 512 + lane * 8;
      ob[t] = (u32)ab.y * 512 + lane * 8;
    }
    float2 v0[8], v1[8], v2[8];
#pragma unroll
    for (int t = 0; t < 8; ++t) {
      v0[t] = ldo<float2>(edge, oe[t]);
      v1[t] = ldo<float2>(node, oa[t]);
      v2[t] = ldo<float2>(node, ob[t]);
    }
#pragma unroll
    for (int t = 0; t < 8; ++t) {
      int lr = wid * 8 + t;
      *(float2*)&er[lr * 128 + 2 * lane] = v0[t];   // cache residual in LDS
      float s  = v0[t].x + v0[t].y + v1[t].x + v1[t].y + v2[t].x + v2[t].y;
      float ss = v0[t].x*v0[t].x + v0[t].y*v0[t].y + v1[t].x*v1[t].x +
                 v1[t].y*v1[t].y + v2[t].x*v2[t].x + v2[t].y*v2[t].y;
#pragma unroll
      for (int m = 1; m < 64; m <<= 1) { s += __shfl_xor(s, m); ss += __shfl_xor(ss, m); }
      float mean = s * (1.0f / 384.0f);
      float var  = ss * (1.0f / 384.0f) - mean * mean;
      float rstd = rsqrtf(var + 1e-5f);
      float2 vv[3] = {v0[t], v1[t], v2[t]};
#pragma unroll
      for (int sg = 0; sg < 3; ++sg) {
        float y0 = (vv[sg].x - mean) * rstd * ga[2 * sg]     + be[2 * sg];
        float y1 = (vv[sg].y - mean) * rstd * ga[2 * sg + 1] + be[2 * sg + 1];
        int sl = (sg * 16 + (lane >> 2)) ^ (lr & 15);
        *(u32*)&xp[lr * 384 + sl * 8 + (lane & 3) * 2] = pk_bf16(y0, y1);
      }
    }
  }
  WAITLGKM0(); SCHEDB(); SBAR(); SCHEDB();

  // ---- gemm1: 12 K-steps, barrier-free; wave owns cols [48*wid, +48) ----
  f32x4 acc1[4][3];
#pragma unroll
  for (int nt = 0; nt < 3; ++nt) {
    float bv = b1[wid * 48 + nt * 16 + l15];
#pragma unroll
    for (int m = 0; m < 4; ++m) acc1[m][nt] = (f32x4){bv, bv, bv, bv};
  }
  int aoff[4];
#pragma unroll
  for (int m = 0; m < 4; ++m) aoff[m] = (m * 16 + l15) * 384;

#pragma unroll
  for (int s = 0; s < 12; ++s) {
    const int axi = ((s * 4 + gq) ^ l15) * 8;
    bf16x8 a[4];
#pragma unroll
    for (int m = 0; m < 4; ++m) a[m] = *(const bf16x8*)&xp[aoff[m] + axi];
    __builtin_amdgcn_s_setprio(1);
#pragma unroll
    for (int m = 0; m < 4; ++m)
#pragma unroll
      for (int nt = 0; nt < 3; ++nt)
        acc1[m][nt] = __builtin_amdgcn_mfma_f32_16x16x32_bf16(a[m], br[s & 1][nt], acc1[m][nt], 0, 0, 0);
    __builtin_amdgcn_s_setprio(0);
    if (s + 2 < 12) { LDB1(s + 2, s & 1); }
  }
  SCHEDB(); SBAR(); SCHEDB();   // all x-reads done before h overwrites xp

  // ---- W2 B-stream prologue + gelu -> h into xp (same swizzle, pitch 384) ----
  const bf16x8* w2v = (const bf16x8*)w2r + (size_t)wid * (12 * 64) + lane;
  bf16x8 br2[2];
#define LDB2(s, b) { br2[b] = w2v[(s) * 64]; }
  LDB2(0, 0); LDB2(1, 1);
#pragma unroll
  for (int m = 0; m < 4; ++m)
#pragma unroll
    for (int nt = 0; nt < 3; ++nt) {
      const int c = wid * 48 + nt * 16 + l15;
#pragma unroll
      for (int j = 0; j < 4; ++j) {
        int r = m * 16 + gq * 4 + j;
        xp[r * 384 + (((c >> 3) ^ (r & 15)) * 8) + (c & 7)] = f2bf_fast(gelu_f(acc1[m][nt][j]));
      }
    }
  WAITLGKM0(); SCHEDB(); SBAR(); SCHEDB();

  // ---- gemm2: 12 K-steps, barrier-free; wave owns cols [16*wid, +16) ----
  float b2v = b2[wid * 16 + l15];
  f32x4 acc2[4];
#pragma unroll
  for (int m = 0; m < 4; ++m) acc2[m] = (f32x4){b2v, b2v, b2v, b2v};

#pragma unroll
  for (int g = 0; g < 12; ++g) {
    const int axi = ((g * 4 + gq) ^ l15) * 8;
    bf16x8 a[4];
#pragma unroll
    for (int m = 0; m < 4; ++m) a[m] = *(const bf16x8*)&xp[aoff[m] + axi];
    __builtin_amdgcn_s_setprio(1);
#pragma unroll
    for (int m = 0; m < 4; ++m)
      acc2[m] = __builtin_amdgcn_mfma_f32_16x16x32_bf16(a[m], br2[g & 1], acc2[m], 0, 0, 0);
    __builtin_amdgcn_s_setprio(0);
    if (g + 2 < 12) { LDB2(g + 2, g & 1); }
  }

  // ---- epilogue: own 16 cols; residual from LDS ----
  const int col = wid * 16 + l15;
#pragma unroll
  for (int m = 0; m < 4; ++m)
#pragma unroll
    for (int j = 0; j < 4; ++j) {
      int lr = m * 16 + gq * 4 + j;
      int r = row0 + lr;
      if (r < N_EDGE) {
        __half hv = __float2half(acc2[m][j]);
        if (store_eh) sto<__half>(e_h, (u32)r * 256 + col * 2, hv);
        sto<float>(out_edge, (u32)r * 512 + col * 4, er[lr * 128 + col] + __half2float(hv));
      }
    }
#undef LDB1
#undef LDB2
}

// ==================== fused node MLP =========================================
// K=256 (8 steps), full x (64x256, 32KB) + node residual (32KB) in LDS;
// 3 barriers; B reg-streamed. LDS 64KB -> 2 blocks/CU.
__global__ __launch_bounds__(512, 4) void node_fused_kernel(
    const float* __restrict__ node, const __half* __restrict__ agg,
    const float* __restrict__ lng, const float* __restrict__ lnb,
    const u16* __restrict__ w1r, const float* __restrict__ b1,
    const u16* __restrict__ w2r, const float* __restrict__ b2,
    float* __restrict__ out_node) {
  const int lane = threadIdx.x & 63, wid = threadIdx.x >> 6;
  const int l15 = lane & 15, gq = lane >> 4;
  const int row0 = blockIdx.x * 64;

  __shared__ __align__(16) u16 xp[64 * 256];      // 32 KB: x, then h
  __shared__ __align__(16) float nr[64 * 128];    // 32 KB: node residual cache

  const bf16x8* w1v = (const bf16x8*)w1r + (size_t)wid * (8 * 128) + lane;
  bf16x8 br[2][2];
#define NLDB1(s, b) { br[b][0] = w1v[(s) * 128]; br[b][1] = w1v[(s) * 128 + 64]; }
  NLDB1(0, 0); NLDB1(1, 1);

  float ga[4], be[4];
#pragma unroll
  for (int s = 0; s < 2; ++s) {
    float2 g2 = *(const float2*)&lng[s * 128 + 2 * lane];
    float2 b2v = *(const float2*)&lnb[s * 128 + 2 * lane];
    ga[2 * s] = g2.x; ga[2 * s + 1] = g2.y;
    be[2 * s] = b2v.x; be[2 * s + 1] = b2v.y;
  }
  {
    float2 v0[8], v1[8];
#pragma unroll
    for (int t = 0; t < 8; ++t) {
      int g = row0 + wid * 8 + t; if (g > N_NODE - 1) g = N_NODE - 1;
      v0[t] = ldo<float2>(node, (u32)g * 512 + lane * 8);
      v1[t] = __half22float2(ldo<__half2>(agg, (u32)g * 256 + lane * 4));
    }
#pragma unroll
    for (int t = 0; t < 8; ++t) {
      int lr = wid * 8 + t;
      *(float2*)&nr[lr * 128 + 2 * lane] = v0[t];   // cache residual
      float s  = v0[t].x + v0[t].y + v1[t].x + v1[t].y;
      float ss = v0[t].x*v0[t].x + v0[t].y*v0[t].y + v1[t].x*v1[t].x + v1[t].y*v1[t].y;
#pragma unroll
      for (int m = 1; m < 64; m <<= 1) { s += __shfl_xor(s, m); ss += __shfl_xor(ss, m); }
      float mean = s * (1.0f / 256.0f);
      float var  = ss * (1.0f / 256.0f) - mean * mean;
      float rstd = rsqrtf(var + 1e-5f);
      float2 vv[2] = {v0[t], v1[t]};
#pragma unroll
      for (int sg = 0; sg < 2; ++sg) {
        float y0 = (vv[sg].x - mean) * rstd * ga[2 * sg]     + be[2 * sg];
        float y1 = (vv[sg].y - mean) * rstd * ga[2 * sg + 1] + be[2 * sg + 1];
        int sl = (sg * 16 + (lane >> 2)) ^ (lr & 15);
        *(u32*)&xp[lr * 256 + sl * 8 + (lane & 3) * 2] = pk_bf16(y0, y1);
      }
    }
  }
  WAITLGKM0(); SCHEDB(); SBAR(); SCHEDB();

  // ---- gemm1: 8 K-steps barrier-free; wave owns cols [32*wid, +32) ----
  f32x4 acc1[4][2];
#pragma unroll
  for (int nt = 0; nt < 2; ++nt) {
    float bv = b1[wid * 32 + nt * 16 + l15];
#pragma unroll
    for (int m = 0; m < 4; ++m) acc1[m][nt] = (f32x4){bv, bv, bv, bv};
  }
  int aoff[4];
#pragma unroll
  for (int m = 0; m < 4; ++m) aoff[m] = (m * 16 + l15) * 256;

#pragma unroll
  for (int s = 0; s < 8; ++s) {
    const int axi = ((s * 4 + gq) ^ l15) * 8;
    bf16x8 a[4];
#pragma unroll
    for (int m = 0; m < 4; ++m) a[m] = *(const bf16x8*)&xp[aoff[m] + axi];
    __builtin_amdgcn_s_setprio(1);
#pragma unroll
    for (int m = 0; m < 4; ++m)
#pragma unroll
      for (int nt = 0; nt < 2; ++nt)
        acc1[m][nt] = __builtin_amdgcn_mfma_f32_16x16x32_bf16(a[m], br[s & 1][nt], acc1[m][nt], 0, 0, 0);
    __builtin_amdgcn_s_setprio(0);
    if (s + 2 < 8) { NLDB1(s + 2, s & 1); }
  }
  SCHEDB(); SBAR(); SCHEDB();

  // ---- W2 prologue + gelu -> h ----
  const bf16x8* w2v = (const bf16x8*)w2r + (size_t)wid * (8 * 64) + lane;
  bf16x8 br2[2];
#define NLDB2(s, b) { br2[b] = w2v[(s) * 64]; }
  NLDB2(0, 0); NLDB2(1, 1);
#pragma unroll
  for (int m = 0; m < 4; ++m)
#pragma unroll
    for (int nt = 0; nt < 2; ++nt) {
      const int c = wid * 32 + nt * 16 + l15;   // 0..255
#pragma unroll
      for (int j = 0; j < 4; ++j) {
        int r = m * 16 + gq * 4 + j;
        xp[r * 256 + (((c >> 3) ^ (r & 15)) * 8) + (c & 7)] = f2bf_fast(gelu_f(acc1[m][nt][j]));
      }
    }
  WAITLGKM0(); SCHEDB(); SBAR(); SCHEDB();

  // ---- gemm2: 8 K-steps barrier-free; wave owns cols [16*wid, +16) ----
  float b2v = b2[wid * 16 + l15];
  f32x4 acc2[4];
#pragma unroll
  for (int m = 0; m < 4; ++m) acc2[m] = (f32x4){b2v, b2v, b2v, b2v};

#pragma unroll
  for (int g = 0; g < 8; ++g) {
    const int axi = ((g * 4 + gq) ^ l15) * 8;
    bf16x8 a[4];
#pragma unroll
    for (int m = 0; m < 4; ++m) a[m] = *(const bf16x8*)&xp[aoff[m] + axi];
    __builtin_amdgcn_s_setprio(1);
#pragma unroll
    for (int m = 0; m < 4; ++m)
      acc2[m] = __builtin_amdgcn_mfma_f32_16x16x32_bf16(a[m], br2[g & 1], acc2[m], 0, 0, 0);
    __builtin_amdgcn_s_setprio(0);
    if (g + 2 < 8) { NLDB2(g + 2, g & 1); }
  }

  const int col = wid * 16 + l15;
#pragma unroll
  for (int m = 0; m < 4; ++m)
#pragma unroll
    for (int j = 0; j < 4; ++j) {
      int lr = m * 16 + gq * 4 + j;
      int r = row0 + lr;
      if (r < N_NODE) {
        sto<float>(out_node, (u32)r * 512 + col * 4, nr[lr * 128 + col] + acc2[m][j]);
      }
    }
#undef NLDB1
#undef NLDB2
}

// ---------------- scatter: 1 nnz/wave, dense 256B rows; scalar nnz loads -----
__global__ __launch_bounds__(256) void scatter_kernel(
    const int* __restrict__ rows, const int* __restrict__ cols,
    const float* __restrict__ vals,
    const __half* __restrict__ e_h,
    const float* __restrict__ out_edge, const float* __restrict__ edge,
    __half* __restrict__ agg, int use_eh) {
  int k = __builtin_amdgcn_readfirstlane(blockIdx.x * 4 + (threadIdx.x >> 6));
  int l = threadIdx.x & 63;
  int r = rows[k], c = cols[k];
  float v = vals[k];
  __half2 h2;
  if (use_eh) {
    h2 = *(const __half2*)&e_h[(size_t)c * 128 + 2 * l];
  } else {
    size_t o = (size_t)c * 128 + 2 * l;
    float2 eo = *(const float2*)&out_edge[o];
    float2 e0 = *(const float2*)&edge[o];
    h2 = __floats2half2_rn(eo.x - e0.x, eo.y - e0.y);
  }
  h2 = __hmul2(h2, __float2half2_rn(v));
  unsafeAtomicAdd((__half2*)&agg[(size_t)r * 128 + 2 * l], h2);
}

extern "C" void kernel_launch(void* const* d_in, const int* in_sizes, int n_in,
                              void* d_out, int out_size, void* d_ws, size_t ws_size,
                              hipStream_t stream) {
  (void)in_sizes; (void)n_in; (void)out_size;
  const float* node    = (const float*)d_in[0];
  const float* edge    = (const float*)d_in[1];
  const int*   edgeIdx = (const int*)d_in[2];
  const int*   e2n_r   = (const int*)d_in[3];
  const int*   e2n_c   = (const int*)d_in[4];
  const float* e2n_v   = (const float*)d_in[5];
  const float* n1g     = (const float*)d_in[6];
  const float* n1b     = (const float*)d_in[7];
  const float* n2g     = (const float*)d_in[8];
  const float* n2b     = (const float*)d_in[9];
  const float* ew1     = (const float*)d_in[10];
  const float* eb1     = (const float*)d_in[11];
  const float* ew2     = (const float*)d_in[12];
  const float* eb2     = (const float*)d_in[13];
  const float* nw1     = (const float*)d_in[14];
  const float* nb1     = (const float*)d_in[15];
  const float* nw2     = (const float*)d_in[16];
  const float* nb2     = (const float*)d_in[17];

  float* out_node = (float*)d_out;
  float* out_edge = out_node + (size_t)N_NODE * 128;

  char* w = (char*)d_ws;
  auto alloc = [&](size_t bytes) { char* p = w; w += (bytes + 255) & ~(size_t)255; return p; };
  u16* ew1r = (u16*)alloc((size_t)384 * 384 * 2);
  u16* ew2r = (u16*)alloc((size_t)384 * 128 * 2);
  u16* nw1r = (u16*)alloc((size_t)256 * 256 * 2);
  u16* nw2r = (u16*)alloc((size_t)256 * 128 * 2);
  __half* agg = (__half*)alloc((size_t)N_NODE * 128 * 2);

  size_t used = (size_t)(w - (char*)d_ws);
  const size_t EH_BYTES = (size_t)N_EDGE * 128 * 2;   // 64 MB
  int use_eh = (ws_size >= used + EH_BYTES) ? 1 : 0;
  __half* e_h = nullptr;
  if (use_eh) e_h = (__half*)alloc(EH_BYTES);

  prep_kernel<<<1024, 256, 0, stream>>>(ew1, ew2, nw1, nw2,
                                        ew1r, ew2r, nw1r, nw2r, (u32*)agg);

  edge_fused_kernel<<<(N_EDGE + 63) / 64, 512, 0, stream>>>(
      node, edge, edgeIdx, n1g, n1b, ew1r, eb1, ew2r, eb2, e_h, out_edge, use_eh);

  scatter_kernel<<<(NNZV + 3) / 4, 256, 0, stream>>>(
      e2n_r, e2n_c, e2n_v, e_h, out_edge, edge, agg, use_eh);

  node_fused_kernel<<<(N_NODE + 63) / 64, 512, 0, stream>>>(
      node, agg, n2g, n2b, nw1r, nb1, nw2r, nb2, out_node);
}

// Round 17
// 345.179 us; speedup vs baseline: 2.9184x; 1.0039x over previous
//
#include <hip/hip_runtime.h>
#include <hip/hip_fp16.h>

typedef unsigned short u16;
typedef unsigned int u32;

#define N_NODE 50000
#define N_EDGE 250000
#define NNZV   500000

typedef __attribute__((ext_vector_type(8))) __bf16 bf16x8;
typedef __attribute__((ext_vector_type(4))) float f32x4;

#define WAITLGKM0() asm volatile("s_waitcnt lgkmcnt(0)" ::: "memory")
#define SBAR() __builtin_amdgcn_s_barrier()
#define SCHEDB() __builtin_amdgcn_sched_barrier(0)

static __device__ __forceinline__ u16 f2bf(float f) {
  union { float f; u32 u; } cv; cv.f = f;
  u32 u = cv.u;
  return (u16)((u + 0x7FFFu + ((u >> 16) & 1u)) >> 16);
}

// packed f32x2 -> bf16x2 (RNE), 1 VALU op
static __device__ __forceinline__ u32 pk_bf16(float lo, float hi) {
  u32 r;
  asm("v_cvt_pk_bf16_f32 %0, %1, %2" : "=v"(r) : "v"(lo), "v"(hi));
  return r;
}

// single f32 -> bf16 via cvt_pk (1 VALU)
static __device__ __forceinline__ u16 f2bf_fast(float x) {
  return (u16)pk_bf16(x, x);
}

template<typename T>
static __device__ __forceinline__ T ldo(const void* base, u32 off) {
  return *(const T*)((const char*)base + off);
}
template<typename T>
static __device__ __forceinline__ void sto(void* base, u32 off, T v) {
  *(T*)((char*)base + off) = v;
}

// exact-erf gelu via A&S 7.1.26 poly (|erf err| <= 1.5e-7)
static __device__ __forceinline__ float gelu_f(float x) {
  float z = fabsf(x) * 0.70710678118654752f;
  float t = __builtin_amdgcn_rcpf(1.0f + 0.3275911f * z);
  float p = t * (0.254829592f + t * (-0.284496736f + t * (1.421413741f +
            t * (-1.453152027f + t * 1.061405429f))));
  float er = 1.0f - p * __expf(-z * z);
  er = copysignf(er, x);
  return 0.5f * x * (1.0f + er);
}

// weights [in=K][out=N] f32 -> per-wave register-fragment stream (16x16x32):
// [w = n/cpw][ks = k/32][t = (n%cpw)/16][lane = (k%32)/8*16 + n%16][e = k%8]
static __device__ __forceinline__ void wconv(const float* __restrict__ in,
                                             u16* __restrict__ out,
                                             int K, int N, int cpw, int idx) {
  int k = idx / N, n = idx % N;
  int w = n / cpw, rem = n % cpw;
  int t = rem >> 4, l15 = rem & 15;
  int ks = k >> 5, gq = (k >> 3) & 3, e = k & 7;
  int steps = K >> 5, tiles = cpw >> 4;
  size_t o = ((((size_t)(w * steps + ks) * tiles + t) * 64) + gq * 16 + l15) * 8 + e;
  out[o] = f2bf(in[(size_t)k * N + n]);
}

// merged prep: 4 weight re-layouts + agg zero-fill, one launch
__global__ __launch_bounds__(256) void prep_kernel(
    const float* __restrict__ ew1, const float* __restrict__ ew2,
    const float* __restrict__ nw1, const float* __restrict__ nw2,
    u16* __restrict__ ew1r, u16* __restrict__ ew2r,
    u16* __restrict__ nw1r, u16* __restrict__ nw2r,
    u32* __restrict__ agg0) {
  const int S1 = 384 * 384, S2 = 384 * 128, S3 = 256 * 256, S4 = 256 * 128;
  const int SA = N_NODE * 128 / 2;   // agg as u32
  const long total = (long)S1 + S2 + S3 + S4 + SA;
  for (long i = (long)blockIdx.x * 256 + threadIdx.x; i < total;
       i += (long)gridDim.x * 256) {
    long idx = i;
    if (idx < S1) { wconv(ew1, ew1r, 384, 384, 48, (int)idx); continue; }
    idx -= S1;
    if (idx < S2) { wconv(ew2, ew2r, 384, 128, 16, (int)idx); continue; }
    idx -= S2;
    if (idx < S3) { wconv(nw1, nw1r, 256, 256, 32, (int)idx); continue; }
    idx -= S3;
    if (idx < S4) { wconv(nw2, nw2r, 256, 128, 16, (int)idx); continue; }
    idx -= S4;
    agg0[idx] = 0;
  }
}

// ==================== fused edge MLP =========================================
// 64 rows/block, 512 thr (8 waves x 48 cols gemm1 / 16 cols gemm2).
// B register-streamed from L2 via RING-3 (prefetch distance ~3 steps covers
// L2 latency). FULL x (64x384, 48KB) in LDS (slot^(row&15) swizzle) ->
// barrier-free K-loops; h overwrites x in place. Edge residual cached in
// 32KB LDS. LDS 80KB -> 2 blocks/CU. launch_bounds(512,4) (r14: 6/EU spills).
__global__ __launch_bounds__(512, 4) void edge_fused_kernel(
    const float* __restrict__ node, const float* __restrict__ edge,
    const int* __restrict__ edgeIdx,
    const float* __restrict__ lng, const float* __restrict__ lnb,
    const u16* __restrict__ w1r, const float* __restrict__ b1,
    const u16* __restrict__ w2r, const float* __restrict__ b2,
    __half* __restrict__ e_h, float* __restrict__ out_edge, int store_eh) {
  const int lane = threadIdx.x & 63, wid = threadIdx.x >> 6;   // 0..7
  const int l15 = lane & 15, gq = lane >> 4;
  const int row0 = blockIdx.x * 64;

  __shared__ __align__(16) u16 xp[64 * 384];      // 48 KB: x, then h (in place)
  __shared__ __align__(16) float er[64 * 128];    // 32 KB: edge residual cache

  // ---- B-stream prologue: W1 steps 0,1,2 into ring-3 registers ----
  const bf16x8* w1v = (const bf16x8*)w1r + (size_t)wid * (12 * 192) + lane;
  bf16x8 br[3][3];
#define LDB1(s, b) { br[b][0] = w1v[(s) * 192]; br[b][1] = w1v[(s) * 192 + 64]; \
                     br[b][2] = w1v[(s) * 192 + 128]; }
  LDB1(0, 0); LDB1(1, 1); LDB1(2, 2);

  // ---- LN + gather: 8 rows/wave ----
  float ga[6], be[6];
#pragma unroll
  for (int s = 0; s < 3; ++s) {
    float2 g2 = *(const float2*)&lng[s * 128 + 2 * lane];
    float2 b2v = *(const float2*)&lnb[s * 128 + 2 * lane];
    ga[2 * s] = g2.x; ga[2 * s + 1] = g2.y;
    be[2 * s] = b2v.x; be[2 * s + 1] = b2v.y;
  }
  {
    u32 oe[8], oa[8], ob[8];
#pragma unroll
    for (int t = 0; t < 8; ++t) {
      int g = row0 + wid * 8 + t; if (g > N_EDGE - 1) g = N_EDGE - 1;
      int2 ab = ldo<int2>(edgeIdx, (u32)g * 8);
      oe[t] = (u32)g * 512 + lane * 8;
      oa[t] = (u32)ab.x * 512 + lane * 8;
      ob[t] = (u32)ab.y * 512 + lane * 8;
    }
    float2 v0[8], v1[8], v2[8];
#pragma unroll
    for (int t = 0; t < 8; ++t) {
      v0[t] = ldo<float2>(edge, oe[t]);
      v1[t] = ldo<float2>(node, oa[t]);
      v2[t] = ldo<float2>(node, ob[t]);
    }
#pragma unroll
    for (int t = 0; t < 8; ++t) {
      int lr = wid * 8 + t;
      *(float2*)&er[lr * 128 + 2 * lane] = v0[t];   // cache residual in LDS
      float s  = v0[t].x + v0[t].y + v1[t].x + v1[t].y + v2[t].x + v2[t].y;
      float ss = v0[t].x*v0[t].x + v0[t].y*v0[t].y + v1[t].x*v1[t].x +
                 v1[t].y*v1[t].y + v2[t].x*v2[t].x + v2[t].y*v2[t].y;
#pragma unroll
      for (int m = 1; m < 64; m <<= 1) { s += __shfl_xor(s, m); ss += __shfl_xor(ss, m); }
      float mean = s * (1.0f / 384.0f);
      float var  = ss * (1.0f / 384.0f) - mean * mean;
      float rstd = rsqrtf(var + 1e-5f);
      float2 vv[3] = {v0[t], v1[t], v2[t]};
#pragma unroll
      for (int sg = 0; sg < 3; ++sg) {
        float y0 = (vv[sg].x - mean) * rstd * ga[2 * sg]     + be[2 * sg];
        float y1 = (vv[sg].y - mean) * rstd * ga[2 * sg + 1] + be[2 * sg + 1];
        int sl = (sg * 16 + (lane >> 2)) ^ (lr & 15);
        *(u32*)&xp[lr * 384 + sl * 8 + (lane & 3) * 2] = pk_bf16(y0, y1);
      }
    }
  }
  WAITLGKM0(); SCHEDB(); SBAR(); SCHEDB();

  // ---- gemm1: 12 K-steps, barrier-free; wave owns cols [48*wid, +48) ----
  f32x4 acc1[4][3];
#pragma unroll
  for (int nt = 0; nt < 3; ++nt) {
    float bv = b1[wid * 48 + nt * 16 + l15];
#pragma unroll
    for (int m = 0; m < 4; ++m) acc1[m][nt] = (f32x4){bv, bv, bv, bv};
  }
  int aoff[4];
#pragma unroll
  for (int m = 0; m < 4; ++m) aoff[m] = (m * 16 + l15) * 384;

#pragma unroll
  for (int s = 0; s < 12; ++s) {
    const int axi = ((s * 4 + gq) ^ l15) * 8;
    bf16x8 a[4];
#pragma unroll
    for (int m = 0; m < 4; ++m) a[m] = *(const bf16x8*)&xp[aoff[m] + axi];
    __builtin_amdgcn_s_setprio(1);
#pragma unroll
    for (int m = 0; m < 4; ++m)
#pragma unroll
      for (int nt = 0; nt < 3; ++nt)
        acc1[m][nt] = __builtin_amdgcn_mfma_f32_16x16x32_bf16(a[m], br[s % 3][nt], acc1[m][nt], 0, 0, 0);
    __builtin_amdgcn_s_setprio(0);
    if (s + 3 < 12) { LDB1(s + 3, s % 3); }
  }
  SCHEDB(); SBAR(); SCHEDB();   // all x-reads done before h overwrites xp

  // ---- W2 B-stream prologue + gelu -> h into xp (same swizzle, pitch 384) ----
  const bf16x8* w2v = (const bf16x8*)w2r + (size_t)wid * (12 * 64) + lane;
  bf16x8 br2[3];
#define LDB2(s, b) { br2[b] = w2v[(s) * 64]; }
  LDB2(0, 0); LDB2(1, 1); LDB2(2, 2);
#pragma unroll
  for (int m = 0; m < 4; ++m)
#pragma unroll
    for (int nt = 0; nt < 3; ++nt) {
      const int c = wid * 48 + nt * 16 + l15;
#pragma unroll
      for (int j = 0; j < 4; ++j) {
        int r = m * 16 + gq * 4 + j;
        xp[r * 384 + (((c >> 3) ^ (r & 15)) * 8) + (c & 7)] = f2bf_fast(gelu_f(acc1[m][nt][j]));
      }
    }
  WAITLGKM0(); SCHEDB(); SBAR(); SCHEDB();

  // ---- gemm2: 12 K-steps, barrier-free; wave owns cols [16*wid, +16) ----
  float b2v = b2[wid * 16 + l15];
  f32x4 acc2[4];
#pragma unroll
  for (int m = 0; m < 4; ++m) acc2[m] = (f32x4){b2v, b2v, b2v, b2v};

#pragma unroll
  for (int g = 0; g < 12; ++g) {
    const int axi = ((g * 4 + gq) ^ l15) * 8;
    bf16x8 a[4];
#pragma unroll
    for (int m = 0; m < 4; ++m) a[m] = *(const bf16x8*)&xp[aoff[m] + axi];
    __builtin_amdgcn_s_setprio(1);
#pragma unroll
    for (int m = 0; m < 4; ++m)
      acc2[m] = __builtin_amdgcn_mfma_f32_16x16x32_bf16(a[m], br2[g % 3], acc2[m], 0, 0, 0);
    __builtin_amdgcn_s_setprio(0);
    if (g + 3 < 12) { LDB2(g + 3, g % 3); }
  }

  // ---- epilogue: own 16 cols; residual from LDS ----
  const int col = wid * 16 + l15;
#pragma unroll
  for (int m = 0; m < 4; ++m)
#pragma unroll
    for (int j = 0; j < 4; ++j) {
      int lr = m * 16 + gq * 4 + j;
      int r = row0 + lr;
      if (r < N_EDGE) {
        __half hv = __float2half(acc2[m][j]);
        if (store_eh) sto<__half>(e_h, (u32)r * 256 + col * 2, hv);
        sto<float>(out_edge, (u32)r * 512 + col * 4, er[lr * 128 + col] + __half2float(hv));
      }
    }
#undef LDB1
#undef LDB2
}

// ==================== fused node MLP =========================================
// K=256 (8 steps), full x (64x256, 32KB) + node residual (32KB) in LDS;
// 3 barriers; B reg-streamed ring-3. LDS 64KB -> 2 blocks/CU.
__global__ __launch_bounds__(512, 4) void node_fused_kernel(
    const float* __restrict__ node, const __half* __restrict__ agg,
    const float* __restrict__ lng, const float* __restrict__ lnb,
    const u16* __restrict__ w1r, const float* __restrict__ b1,
    const u16* __restrict__ w2r, const float* __restrict__ b2,
    float* __restrict__ out_node) {
  const int lane = threadIdx.x & 63, wid = threadIdx.x >> 6;
  const int l15 = lane & 15, gq = lane >> 4;
  const int row0 = blockIdx.x * 64;

  __shared__ __align__(16) u16 xp[64 * 256];      // 32 KB: x, then h
  __shared__ __align__(16) float nr[64 * 128];    // 32 KB: node residual cache

  const bf16x8* w1v = (const bf16x8*)w1r + (size_t)wid * (8 * 128) + lane;
  bf16x8 br[3][2];
#define NLDB1(s, b) { br[b][0] = w1v[(s) * 128]; br[b][1] = w1v[(s) * 128 + 64]; }
  NLDB1(0, 0); NLDB1(1, 1); NLDB1(2, 2);

  float ga[4], be[4];
#pragma unroll
  for (int s = 0; s < 2; ++s) {
    float2 g2 = *(const float2*)&lng[s * 128 + 2 * lane];
    float2 b2v = *(const float2*)&lnb[s * 128 + 2 * lane];
    ga[2 * s] = g2.x; ga[2 * s + 1] = g2.y;
    be[2 * s] = b2v.x; be[2 * s + 1] = b2v.y;
  }
  {
    float2 v0[8], v1[8];
#pragma unroll
    for (int t = 0; t < 8; ++t) {
      int g = row0 + wid * 8 + t; if (g > N_NODE - 1) g = N_NODE - 1;
      v0[t] = ldo<float2>(node, (u32)g * 512 + lane * 8);
      v1[t] = __half22float2(ldo<__half2>(agg, (u32)g * 256 + lane * 4));
    }
#pragma unroll
    for (int t = 0; t < 8; ++t) {
      int lr = wid * 8 + t;
      *(float2*)&nr[lr * 128 + 2 * lane] = v0[t];   // cache residual
      float s  = v0[t].x + v0[t].y + v1[t].x + v1[t].y;
      float ss = v0[t].x*v0[t].x + v0[t].y*v0[t].y + v1[t].x*v1[t].x + v1[t].y*v1[t].y;
#pragma unroll
      for (int m = 1; m < 64; m <<= 1) { s += __shfl_xor(s, m); ss += __shfl_xor(ss, m); }
      float mean = s * (1.0f / 256.0f);
      float var  = ss * (1.0f / 256.0f) - mean * mean;
      float rstd = rsqrtf(var + 1e-5f);
      float2 vv[2] = {v0[t], v1[t]};
#pragma unroll
      for (int sg = 0; sg < 2; ++sg) {
        float y0 = (vv[sg].x - mean) * rstd * ga[2 * sg]     + be[2 * sg];
        float y1 = (vv[sg].y - mean) * rstd * ga[2 * sg + 1] + be[2 * sg + 1];
        int sl = (sg * 16 + (lane >> 2)) ^ (lr & 15);
        *(u32*)&xp[lr * 256 + sl * 8 + (lane & 3) * 2] = pk_bf16(y0, y1);
      }
    }
  }
  WAITLGKM0(); SCHEDB(); SBAR(); SCHEDB();

  // ---- gemm1: 8 K-steps barrier-free; wave owns cols [32*wid, +32) ----
  f32x4 acc1[4][2];
#pragma unroll
  for (int nt = 0; nt < 2; ++nt) {
    float bv = b1[wid * 32 + nt * 16 + l15];
#pragma unroll
    for (int m = 0; m < 4; ++m) acc1[m][nt] = (f32x4){bv, bv, bv, bv};
  }
  int aoff[4];
#pragma unroll
  for (int m = 0; m < 4; ++m) aoff[m] = (m * 16 + l15) * 256;

#pragma unroll
  for (int s = 0; s < 8; ++s) {
    const int axi = ((s * 4 + gq) ^ l15) * 8;
    bf16x8 a[4];
#pragma unroll
    for (int m = 0; m < 4; ++m) a[m] = *(const bf16x8*)&xp[aoff[m] + axi];
    __builtin_amdgcn_s_setprio(1);
#pragma unroll
    for (int m = 0; m < 4; ++m)
#pragma unroll
      for (int nt = 0; nt < 2; ++nt)
        acc1[m][nt] = __builtin_amdgcn_mfma_f32_16x16x32_bf16(a[m], br[s % 3][nt], acc1[m][nt], 0, 0, 0);
    __builtin_amdgcn_s_setprio(0);
    if (s + 3 < 8) { NLDB1(s + 3, s % 3); }
  }
  SCHEDB(); SBAR(); SCHEDB();

  // ---- W2 prologue + gelu -> h ----
  const bf16x8* w2v = (const bf16x8*)w2r + (size_t)wid * (8 * 64) + lane;
  bf16x8 br2[3];
#define NLDB2(s, b) { br2[b] = w2v[(s) * 64]; }
  NLDB2(0, 0); NLDB2(1, 1); NLDB2(2, 2);
#pragma unroll
  for (int m = 0; m < 4; ++m)
#pragma unroll
    for (int nt = 0; nt < 2; ++nt) {
      const int c = wid * 32 + nt * 16 + l15;   // 0..255
#pragma unroll
      for (int j = 0; j < 4; ++j) {
        int r = m * 16 + gq * 4 + j;
        xp[r * 256 + (((c >> 3) ^ (r & 15)) * 8) + (c & 7)] = f2bf_fast(gelu_f(acc1[m][nt][j]));
      }
    }
  WAITLGKM0(); SCHEDB(); SBAR(); SCHEDB();

  // ---- gemm2: 8 K-steps barrier-free; wave owns cols [16*wid, +16) ----
  float b2v = b2[wid * 16 + l15];
  f32x4 acc2[4];
#pragma unroll
  for (int m = 0; m < 4; ++m) acc2[m] = (f32x4){b2v, b2v, b2v, b2v};

#pragma unroll
  for (int g = 0; g < 8; ++g) {
    const int axi = ((g * 4 + gq) ^ l15) * 8;
    bf16x8 a[4];
#pragma unroll
    for (int m = 0; m < 4; ++m) a[m] = *(const bf16x8*)&xp[aoff[m] + axi];
    __builtin_amdgcn_s_setprio(1);
#pragma unroll
    for (int m = 0; m < 4; ++m)
      acc2[m] = __builtin_amdgcn_mfma_f32_16x16x32_bf16(a[m], br2[g % 3], acc2[m], 0, 0, 0);
    __builtin_amdgcn_s_setprio(0);
    if (g + 3 < 8) { NLDB2(g + 3, g % 3); }
  }

  const int col = wid * 16 + l15;
#pragma unroll
  for (int m = 0; m < 4; ++m)
#pragma unroll
    for (int j = 0; j < 4; ++j) {
      int lr = m * 16 + gq * 4 + j;
      int r = row0 + lr;
      if (r < N_NODE) {
        sto<float>(out_node, (u32)r * 512 + col * 4, nr[lr * 128 + col] + acc2[m][j]);
      }
    }
#undef NLDB1
#undef NLDB2
}

// ---------------- scatter: 1 nnz/wave, dense 256B rows; scalar nnz loads -----
__global__ __launch_bounds__(256) void scatter_kernel(
    const int* __restrict__ rows, const int* __restrict__ cols,
    const float* __restrict__ vals,
    const __half* __restrict__ e_h,
    const float* __restrict__ out_edge, const float* __restrict__ edge,
    __half* __restrict__ agg, int use_eh) {
  int k = __builtin_amdgcn_readfirstlane(blockIdx.x * 4 + (threadIdx.x >> 6));
  int l = threadIdx.x & 63;
  int r = rows[k], c = cols[k];
  float v = vals[k];
  __half2 h2;
  if (use_eh) {
    h2 = *(const __half2*)&e_h[(size_t)c * 128 + 2 * l];
  } else {
    size_t o = (size_t)c * 128 + 2 * l;
    float2 eo = *(const float2*)&out_edge[o];
    float2 e0 = *(const float2*)&edge[o];
    h2 = __floats2half2_rn(eo.x - e0.x, eo.y - e0.y);
  }
  h2 = __hmul2(h2, __float2half2_rn(v));
  unsafeAtomicAdd((__half2*)&agg[(size_t)r * 128 + 2 * l], h2);
}

extern "C" void kernel_launch(void* const* d_in, const int* in_sizes, int n_in,
                              void* d_out, int out_size, void* d_ws, size_t ws_size,
                              hipStream_t stream) {
  (void)in_sizes; (void)n_in; (void)out_size;
  const float* node    = (const float*)d_in[0];
  const float* edge    = (const float*)d_in[1];
  const int*   edgeIdx = (const int*)d_in[2];
  const int*   e2n_r   = (const int*)d_in[3];
  const int*   e2n_c   = (const int*)d_in[4];
  const float* e2n_v   = (const float*)d_in[5];
  const float* n1g     = (const float*)d_in[6];
  const float* n1b     = (const float*)d_in[7];
  const float* n2g     = (const float*)d_in[8];
  const float* n2b     = (const float*)d_in[9];
  const float* ew1     = (const float*)d_in[10];
  const float* eb1     = (const float*)d_in[11];
  const float* ew2     = (const float*)d_in[12];
  const float* eb2     = (const float*)d_in[13];
  const float* nw1     = (const float*)d_in[14];
  const float* nb1     = (const float*)d_in[15];
  const float* nw2     = (const float*)d_in[16];
  const float* nb2     = (const float*)d_in[17];

  float* out_node = (float*)d_out;
  float* out_edge = out_node + (size_t)N_NODE * 128;

  char* w = (char*)d_ws;
  auto alloc = [&](size_t bytes) { char* p = w; w += (bytes + 255) & ~(size_t)255; return p; };
  u16* ew1r = (u16*)alloc((size_t)384 * 384 * 2);
  u16* ew2r = (u16*)alloc((size_t)384 * 128 * 2);
  u16* nw1r = (u16*)alloc((size_t)256 * 256 * 2);
  u16* nw2r = (u16*)alloc((size_t)256 * 128 * 2);
  __half* agg = (__half*)alloc((size_t)N_NODE * 128 * 2);

  size_t used = (size_t)(w - (char*)d_ws);
  const size_t EH_BYTES = (size_t)N_EDGE * 128 * 2;   // 64 MB
  int use_eh = (ws_size >= used + EH_BYTES) ? 1 : 0;
  __half* e_h = nullptr;
  if (use_eh) e_h = (__half*)alloc(EH_BYTES);

  prep_kernel<<<1024, 256, 0, stream>>>(ew1, ew2, nw1, nw2,
                                        ew1r, ew2r, nw1r, nw2r, (u32*)agg);

  edge_fused_kernel<<<(N_EDGE + 63) / 64, 512, 0, stream>>>(
      node, edge, edgeIdx, n1g, n1b, ew1r, eb1, ew2r, eb2, e_h, out_edge, use_eh);

  scatter_kernel<<<(NNZV + 3) / 4, 256, 0, stream>>>(
      e2n_r, e2n_c, e2n_v, e_h, out_edge, edge, agg, use_eh);

  node_fused_kernel<<<(N_NODE + 63) / 64, 512, 0, stream>>>(
      node, agg, n2g, n2b, nw1r, nb1, nw2r, nb2, out_node);
}